// Round 5
// baseline (168.807 us; speedup 1.0000x reference)
//
#include <hip/hip_runtime.h>
#include <cstdint>
#include <cstddef>

typedef short bfrag  __attribute__((ext_vector_type(8)));   // 8 bf16 (4 VGPR)
typedef float facc   __attribute__((ext_vector_type(4)));   // 4 f32
typedef float f32x16 __attribute__((ext_vector_type(16)));  // 32x32 acc
typedef float f32x4v __attribute__((ext_vector_type(4)));   // indexable float4

namespace {
constexpr int B = 128, N = 2048, A = 16, M = 64, D = 16;
constexpr int NA = N * A;            // 32768 (GEMM K)
constexpr int MD = M * D;            // 1024  (GEMM N)
constexpr size_t C_ELEMS = (size_t)B * MD;  // 131072
}

static __device__ __forceinline__ ushort f2bf(float x) {  // RNE f32->bf16
    uint u = __float_as_uint(x);
    u += 0x7fffu + ((u >> 16) & 1u);
    return (ushort)(u >> 16);
}
static __device__ __forceinline__ bfrag ld_frag16(const ushort* p) {  // 16B-aligned
    union { uint4 q; bfrag v; } u;
    u.q = *(const uint4*)p;
    return u.v;
}
static __device__ __forceinline__ bfrag ld_frag4(const ushort* p) {   // 4B-aligned
    const uint* q = (const uint*)p;
    union { uint a[4]; bfrag v; } u;
    u.a[0] = q[0]; u.a[1] = q[1]; u.a[2] = q[2]; u.a[3] = q[3];
    return u.v;
}

// ---------------------------------------------------------------------------
// k1: split-K bf16 MFMA GEMM. part[chunk][b][md] = sum_{na in chunk} in*w
// (unchanged — measured ~84% of its 235 MB HBM floor)
// ---------------------------------------------------------------------------
__global__ __launch_bounds__(512, 2) void k1_mfma(const float* __restrict__ in,
                                                  const float* __restrict__ w,
                                                  float* __restrict__ part,
                                                  int nch) {
    const int mdg   = blockIdx.x;
    const int chunk = blockIdx.y;
    const int t     = threadIdx.x;
    const int nap   = NA / nch;
    const int nkt   = nap / 64;
    __shared__ __align__(16) ushort in_t[128 * 72];
    __shared__ __align__(16) ushort w_t[256 * 66];
    const int wv = t >> 6, tl = t & 63;
    const int wb = wv >> 2, wm = wv & 3;
    const int lr = tl & 15, hi = tl >> 4;

    facc acc[4][4];
    #pragma unroll
    for (int i = 0; i < 4; ++i)
        #pragma unroll
        for (int j = 0; j < 4; ++j) acc[i][j] = facc{0.f, 0.f, 0.f, 0.f};

    float4 pin[4], pw[8];
    const int ib  = t >> 4, ik = t & 15;
    const int wk  = t >> 6, wmd = t & 63;

    int na0 = (size_t)chunk * nap;
    #pragma unroll
    for (int q = 0; q < 4; ++q)
        pin[q] = *(const float4*)(in + (size_t)(q * 32 + ib) * NA + na0 + ik * 4);
    #pragma unroll
    for (int q = 0; q < 8; ++q)
        pw[q] = *(const float4*)(w + (size_t)(na0 + q * 8 + wk) * MD + mdg * 256 + wmd * 4);

    for (int kt = 0; kt < nkt; ++kt) {
        __syncthreads();
        #pragma unroll
        for (int q = 0; q < 4; ++q) {
            union { ushort s[4]; uint2 u; } pk;
            pk.s[0] = f2bf(pin[q].x); pk.s[1] = f2bf(pin[q].y);
            pk.s[2] = f2bf(pin[q].z); pk.s[3] = f2bf(pin[q].w);
            *(uint2*)(&in_t[(q * 32 + ib) * 72 + ik * 4]) = pk.u;
        }
        #pragma unroll
        for (int q = 0; q < 8; ++q) {
            const int krow = q * 8 + wk;
            w_t[(wmd * 4 + 0) * 66 + krow] = f2bf(pw[q].x);
            w_t[(wmd * 4 + 1) * 66 + krow] = f2bf(pw[q].y);
            w_t[(wmd * 4 + 2) * 66 + krow] = f2bf(pw[q].z);
            w_t[(wmd * 4 + 3) * 66 + krow] = f2bf(pw[q].w);
        }
        __syncthreads();
        if (kt + 1 < nkt) {
            const int nan = na0 + 64;
            #pragma unroll
            for (int q = 0; q < 4; ++q)
                pin[q] = *(const float4*)(in + (size_t)(q * 32 + ib) * NA + nan + ik * 4);
            #pragma unroll
            for (int q = 0; q < 8; ++q)
                pw[q] = *(const float4*)(w + (size_t)(nan + q * 8 + wk) * MD + mdg * 256 + wmd * 4);
        }
        #pragma unroll
        for (int ks = 0; ks < 2; ++ks) {
            bfrag af[4], bf[4];
            #pragma unroll
            for (int bt = 0; bt < 4; ++bt)
                af[bt] = ld_frag16(&in_t[(wb * 64 + bt * 16 + lr) * 72 + ks * 32 + hi * 8]);
            #pragma unroll
            for (int mt = 0; mt < 4; ++mt)
                bf[mt] = ld_frag4(&w_t[(wm * 64 + mt * 16 + lr) * 66 + ks * 32 + hi * 8]);
            #pragma unroll
            for (int bt = 0; bt < 4; ++bt)
                #pragma unroll
                for (int mt = 0; mt < 4; ++mt)
                    acc[bt][mt] = __builtin_amdgcn_mfma_f32_16x16x32_bf16(
                        af[bt], bf[mt], acc[bt][mt], 0, 0, 0);
        }
        na0 += 64;
    }
    #pragma unroll
    for (int bt = 0; bt < 4; ++bt)
        #pragma unroll
        for (int mt = 0; mt < 4; ++mt) {
            const int b  = wb * 64 + bt * 16 + hi * 4;
            const int md = mdg * 256 + wm * 64 + mt * 16 + lr;
            #pragma unroll
            for (int r = 0; r < 4; ++r)
                part[((size_t)chunk * B + b + r) * MD + md] = acc[bt][mt][r];
        }
}

// ---------------------------------------------------------------------------
// k2: reduce partials -> v_raw -> squash -> v_sq (ws); LayerNorm -> out_v
// ---------------------------------------------------------------------------
__global__ __launch_bounds__(256) void k2_squash_ln(const float* __restrict__ part,
                                                    const float* __restrict__ gamma,
                                                    const float* __restrict__ beta,
                                                    float* __restrict__ v_sq,
                                                    float* __restrict__ out_v,
                                                    int nch) {
    const int idx = blockIdx.x * 256 + threadIdx.x;
    const int d   = idx & 15;
    float s = 0.f;
    for (int c = 0; c < nch; ++c) s += part[(size_t)c * C_ELEMS + idx];
    const float v = s * (1.0f / 64.0f);
    float sq = v * v;
    #pragma unroll
    for (int off = 1; off < 16; off <<= 1) sq += __shfl_xor(sq, off, 16);
    const float f  = sqrtf(sq) / (1.0f + sq);
    const float vs = v * f;
    v_sq[idx] = vs;
    float mu = vs;
    #pragma unroll
    for (int off = 1; off < 16; off <<= 1) mu += __shfl_xor(mu, off, 16);
    mu *= (1.0f / 16.0f);
    const float dd = vs - mu;
    float var = dd * dd;
    #pragma unroll
    for (int off = 1; off < 16; off <<= 1) var += __shfl_xor(var, off, 16);
    var *= (1.0f / 16.0f);
    out_v[idx] = dd / sqrtf(var + 1e-5f) * gamma[d] + beta[d];
}

// ---------------------------------------------------------------------------
// k3 v4: 32x32x16 MFMA, K = a = 16 exactly (no padding waste).
// qk[b,n,m] = sum_d t[b,n,m,d]*vsq[b,m,d],  t = sum_a in[b,n,a]*w[n,a,m,d]
// grid (8 m-groups of 8, 128 n-segs of 16), 512 thr = 8 waves (4 bg x 2 nn).
// Per (wave, n): 4 MFMA (m-pairs), A = w^T rows=(mj,d) 32, B = in^T cols=b 32.
// C (verified): col=lane&31=b, row=(reg&3)+8*(reg>>2)+4*l5 = (mj,d).
// Epilogue: 8 FMA per mj vs reg-resident vsq d-half + 1 shfl_xor(32).
// LDS XOR-swizzle (bit-4) makes A/B ds_read_b128 <=2-way conflict.
// w read from HBM exactly once (all 128 b in-block). 1-deep reg prefetch.
// ---------------------------------------------------------------------------
__global__ __launch_bounds__(512, 4) void k3_mfma2(const float* __restrict__ in,
                                                   const float* __restrict__ w,
                                                   const float* __restrict__ vsq,
                                                   float* __restrict__ qk) {
    const int mg = blockIdx.x;                        // 8 m per group
    const int m0 = mg * 8;
    const int n0 = blockIdx.y * 16;
    const int t  = threadIdx.x;
    const int wv = t >> 6;
    const int bg = wv & 3, nw = wv >> 2;              // wave: b-group, n-slot
    const int lane = t & 63;
    const int lc = lane & 31, l5 = lane >> 5;
    const int b  = bg * 32 + lc;                      // this lane's b (col)
    const int swb = (lc >> 2) & 1;                    // read-side swizzle bit

    __shared__ __align__(16) ushort wt[4096];  // [nn][mp][row32][a16] swz bit4
    __shared__ __align__(16) ushort it[4096];  // [nn][b128][a16]     swz bit4

    // vsq regs: vr[m][h][e] = vsq[b][m0+m][h*8 + 4*l5 + e]  (lane's d-half)
    f32x4v vr[8][2];
    #pragma unroll
    for (int m = 0; m < 8; ++m) {
        vr[m][0] = *(const f32x4v*)(vsq + ((size_t)b * M + m0 + m) * D + 4 * l5);
        vr[m][1] = *(const f32x4v*)(vsq + ((size_t)b * M + m0 + m) * D + 8 + 4 * l5);
    }

    // staging roles: threads 0-255 stage w, 256-511 stage in (wave-uniform)
    const bool is_w = t < 256;
    const int  su   = t & 255;
    const int s_nn = su >> 7, s_a0 = ((su >> 5) & 3) * 4;   // w-stager coords
    const int s_m  = (su >> 2) & 7, s_d4 = su & 3;
    const int s_b  = su >> 1, s_q = su & 1;                 // in-stager coords

    float4 pr[4];
    auto ldg = [&](int ph) {
        const int nb = n0 + ph * 2;
        if (is_w) {
            const size_t base =
                (((size_t)(nb + s_nn) * A + s_a0) * M + m0 + s_m) * D + s_d4 * 4;
            #pragma unroll
            for (int j = 0; j < 4; ++j)
                pr[j] = *(const float4*)(w + base + (size_t)j * MD);
        } else {
            const float* p = in + (size_t)s_b * NA + (size_t)(nb + s_q) * A;
            #pragma unroll
            for (int j = 0; j < 4; ++j) pr[j] = *(const float4*)(p + j * 4);
        }
    };
    auto stg = [&]() {
        if (is_w) {
            // 4a x 4d reg-transpose -> 4 ushort4 rows (row = mj*16 + d)
            const int mp = s_m >> 1, mj = s_m & 1;
            const int h = s_a0 >> 3, ain = s_a0 & 7;
            const int phys = h ^ (s_d4 & 1);          // (row>>2)&1 == d4&1
            #pragma unroll
            for (int k = 0; k < 4; ++k) {
                const int row = mj * 16 + s_d4 * 4 + k;
                ushort4 v;
                v.x = f2bf(pr[0][k]); v.y = f2bf(pr[1][k]);
                v.z = f2bf(pr[2][k]); v.w = f2bf(pr[3][k]);
                *(ushort4*)(&wt[(s_nn * 4 + mp) * 512 + row * 16 + phys * 8 + ain]) = v;
            }
        } else {
            union { ushort s[8]; uint4 q; } h0, h1;
            h0.s[0] = f2bf(pr[0].x); h0.s[1] = f2bf(pr[0].y);
            h0.s[2] = f2bf(pr[0].z); h0.s[3] = f2bf(pr[0].w);
            h0.s[4] = f2bf(pr[1].x); h0.s[5] = f2bf(pr[1].y);
            h0.s[6] = f2bf(pr[1].z); h0.s[7] = f2bf(pr[1].w);
            h1.s[0] = f2bf(pr[2].x); h1.s[1] = f2bf(pr[2].y);
            h1.s[2] = f2bf(pr[2].z); h1.s[3] = f2bf(pr[2].w);
            h1.s[4] = f2bf(pr[3].x); h1.s[5] = f2bf(pr[3].y);
            h1.s[6] = f2bf(pr[3].z); h1.s[7] = f2bf(pr[3].w);
            const int sw = (s_b >> 2) & 1;
            const int base = (s_q * 128 + s_b) * 16;
            *(uint4*)(&it[base + sw * 8])       = h0.q;   // a 0..7
            *(uint4*)(&it[base + (1 - sw) * 8]) = h1.q;   // a 8..15
        }
    };

    ldg(0);
    for (int ph = 0; ph < 8; ++ph) {
        __syncthreads();                              // prev compute done
        stg();
        __syncthreads();                              // tile ready
        if (ph < 7) ldg(ph + 1);                      // prefetch next (regs)

        const int n = n0 + ph * 2 + nw;
        // B-frag: B[k = l5*8+j, col=b] = in[b, n, a]
        const bfrag bf = ld_frag16(&it[(nw * 128 + b) * 16 + (l5 ^ swb) * 8]);
        float sreg[8];
        #pragma unroll
        for (int mp = 0; mp < 4; ++mp) {
            // A-frag: A[row=lc, k=l5*8+j] = w[n, a, m0+mp*2+(lc>>4), lc&15]
            const bfrag af = ld_frag16(
                &wt[(nw * 4 + mp) * 512 + lc * 16 + (l5 ^ swb) * 8]);
            f32x16 c = {};
            c = __builtin_amdgcn_mfma_f32_32x32x16_bf16(af, bf, c, 0, 0, 0);
            #pragma unroll
            for (int mj = 0; mj < 2; ++mj) {
                float s = 0.f;
                #pragma unroll
                for (int rr = 0; rr < 8; ++rr)
                    s += c[mj * 8 + rr] * vr[mp * 2 + mj][rr >> 2][rr & 3];
                s += __shfl_xor(s, 32);               // add other d-half
                sreg[mp * 2 + mj] = s;
            }
        }
        const float4 o = l5 ? float4{sreg[4], sreg[5], sreg[6], sreg[7]}
                            : float4{sreg[0], sreg[1], sreg[2], sreg[3]};
        *(float4*)(qk + ((size_t)b * N + n) * M + m0 + l5 * 4) = o;
    }
}

// ---------------------------------------------------------------------------
extern "C" void kernel_launch(void* const* d_in, const int* in_sizes, int n_in,
                              void* d_out, int out_size, void* d_ws, size_t ws_size,
                              hipStream_t stream) {
    const float* in    = (const float*)d_in[0];
    const float* w     = (const float*)d_in[1];
    const float* gamma = (const float*)d_in[2];
    const float* beta  = (const float*)d_in[3];
    float* out_qk = (float*)d_out;
    float* out_v  = out_qk + (size_t)B * N * M;

    int nch = 64;
    if (ws_size < (64 + 1) * C_ELEMS * sizeof(float)) nch = 16;
    if (ws_size < (16 + 1) * C_ELEMS * sizeof(float)) nch = 8;
    float* part = (float*)d_ws;
    float* vsq  = part + (size_t)nch * C_ELEMS;

    k1_mfma<<<dim3(4, nch), 512, 0, stream>>>(in, w, part, nch);
    k2_squash_ln<<<(int)(C_ELEMS / 256), 256, 0, stream>>>(part, gamma, beta, vsq, out_v, nch);
    k3_mfma2<<<dim3(8, 128), 512, 0, stream>>>(in, w, vsq, out_qk);
}

// Round 6
// 135.776 us; speedup vs baseline: 1.2433x; 1.2433x over previous
//
#include <hip/hip_runtime.h>
#include <cstdint>
#include <cstddef>

typedef short bfrag  __attribute__((ext_vector_type(8)));   // 8 bf16 (4 VGPR)
typedef float facc   __attribute__((ext_vector_type(4)));   // 4 f32
typedef float f32x16 __attribute__((ext_vector_type(16)));  // 32x32 acc
typedef float f32x4v __attribute__((ext_vector_type(4)));   // indexable float4

namespace {
constexpr int B = 128, N = 2048, A = 16, M = 64, D = 16;
constexpr int NA = N * A;            // 32768 (GEMM K)
constexpr int MD = M * D;            // 1024  (GEMM N)
constexpr size_t C_ELEMS = (size_t)B * MD;  // 131072
constexpr int WP = 24;               // LDS row pitch (ushorts): 48B, 16B-aligned
}

static __device__ __forceinline__ ushort f2bf(float x) {  // RNE f32->bf16
    uint u = __float_as_uint(x);
    u += 0x7fffu + ((u >> 16) & 1u);
    return (ushort)(u >> 16);
}
static __device__ __forceinline__ bfrag ld_frag16(const ushort* p) {  // 16B-aligned
    union { uint4 q; bfrag v; } u;
    u.q = *(const uint4*)p;
    return u.v;
}
static __device__ __forceinline__ bfrag ld_frag4(const ushort* p) {   // 4B-aligned
    const uint* q = (const uint*)p;
    union { uint a[4]; bfrag v; } u;
    u.a[0] = q[0]; u.a[1] = q[1]; u.a[2] = q[2]; u.a[3] = q[3];
    return u.v;
}

// ---------------------------------------------------------------------------
// k1: split-K bf16 MFMA GEMM. part[chunk][b][md] = sum_{na in chunk} in*w
// (unchanged — measured ~84% of its 235 MB HBM floor)
// ---------------------------------------------------------------------------
__global__ __launch_bounds__(512, 2) void k1_mfma(const float* __restrict__ in,
                                                  const float* __restrict__ w,
                                                  float* __restrict__ part,
                                                  int nch) {
    const int mdg   = blockIdx.x;
    const int chunk = blockIdx.y;
    const int t     = threadIdx.x;
    const int nap   = NA / nch;
    const int nkt   = nap / 64;
    __shared__ __align__(16) ushort in_t[128 * 72];
    __shared__ __align__(16) ushort w_t[256 * 66];
    const int wv = t >> 6, tl = t & 63;
    const int wb = wv >> 2, wm = wv & 3;
    const int lr = tl & 15, hi = tl >> 4;

    facc acc[4][4];
    #pragma unroll
    for (int i = 0; i < 4; ++i)
        #pragma unroll
        for (int j = 0; j < 4; ++j) acc[i][j] = facc{0.f, 0.f, 0.f, 0.f};

    float4 pin[4], pw[8];
    const int ib  = t >> 4, ik = t & 15;
    const int wk  = t >> 6, wmd = t & 63;

    int na0 = (size_t)chunk * nap;
    #pragma unroll
    for (int q = 0; q < 4; ++q)
        pin[q] = *(const float4*)(in + (size_t)(q * 32 + ib) * NA + na0 + ik * 4);
    #pragma unroll
    for (int q = 0; q < 8; ++q)
        pw[q] = *(const float4*)(w + (size_t)(na0 + q * 8 + wk) * MD + mdg * 256 + wmd * 4);

    for (int kt = 0; kt < nkt; ++kt) {
        __syncthreads();
        #pragma unroll
        for (int q = 0; q < 4; ++q) {
            union { ushort s[4]; uint2 u; } pk;
            pk.s[0] = f2bf(pin[q].x); pk.s[1] = f2bf(pin[q].y);
            pk.s[2] = f2bf(pin[q].z); pk.s[3] = f2bf(pin[q].w);
            *(uint2*)(&in_t[(q * 32 + ib) * 72 + ik * 4]) = pk.u;
        }
        #pragma unroll
        for (int q = 0; q < 8; ++q) {
            const int krow = q * 8 + wk;
            w_t[(wmd * 4 + 0) * 66 + krow] = f2bf(pw[q].x);
            w_t[(wmd * 4 + 1) * 66 + krow] = f2bf(pw[q].y);
            w_t[(wmd * 4 + 2) * 66 + krow] = f2bf(pw[q].z);
            w_t[(wmd * 4 + 3) * 66 + krow] = f2bf(pw[q].w);
        }
        __syncthreads();
        if (kt + 1 < nkt) {
            const int nan = na0 + 64;
            #pragma unroll
            for (int q = 0; q < 4; ++q)
                pin[q] = *(const float4*)(in + (size_t)(q * 32 + ib) * NA + nan + ik * 4);
            #pragma unroll
            for (int q = 0; q < 8; ++q)
                pw[q] = *(const float4*)(w + (size_t)(nan + q * 8 + wk) * MD + mdg * 256 + wmd * 4);
        }
        #pragma unroll
        for (int ks = 0; ks < 2; ++ks) {
            bfrag af[4], bf[4];
            #pragma unroll
            for (int bt = 0; bt < 4; ++bt)
                af[bt] = ld_frag16(&in_t[(wb * 64 + bt * 16 + lr) * 72 + ks * 32 + hi * 8]);
            #pragma unroll
            for (int mt = 0; mt < 4; ++mt)
                bf[mt] = ld_frag4(&w_t[(wm * 64 + mt * 16 + lr) * 66 + ks * 32 + hi * 8]);
            #pragma unroll
            for (int bt = 0; bt < 4; ++bt)
                #pragma unroll
                for (int mt = 0; mt < 4; ++mt)
                    acc[bt][mt] = __builtin_amdgcn_mfma_f32_16x16x32_bf16(
                        af[bt], bf[mt], acc[bt][mt], 0, 0, 0);
        }
        na0 += 64;
    }
    #pragma unroll
    for (int bt = 0; bt < 4; ++bt)
        #pragma unroll
        for (int mt = 0; mt < 4; ++mt) {
            const int b  = wb * 64 + bt * 16 + hi * 4;
            const int md = mdg * 256 + wm * 64 + mt * 16 + lr;
            #pragma unroll
            for (int r = 0; r < 4; ++r)
                part[((size_t)chunk * B + b + r) * MD + md] = acc[bt][mt][r];
        }
}

// ---------------------------------------------------------------------------
// k2: reduce partials -> v_raw -> squash -> v_sq (ws); LayerNorm -> out_v
// ---------------------------------------------------------------------------
__global__ __launch_bounds__(256) void k2_squash_ln(const float* __restrict__ part,
                                                    const float* __restrict__ gamma,
                                                    const float* __restrict__ beta,
                                                    float* __restrict__ v_sq,
                                                    float* __restrict__ out_v,
                                                    int nch) {
    const int idx = blockIdx.x * 256 + threadIdx.x;
    const int d   = idx & 15;
    float s = 0.f;
    for (int c = 0; c < nch; ++c) s += part[(size_t)c * C_ELEMS + idx];
    const float v = s * (1.0f / 64.0f);
    float sq = v * v;
    #pragma unroll
    for (int off = 1; off < 16; off <<= 1) sq += __shfl_xor(sq, off, 16);
    const float f  = sqrtf(sq) / (1.0f + sq);
    const float vs = v * f;
    v_sq[idx] = vs;
    float mu = vs;
    #pragma unroll
    for (int off = 1; off < 16; off <<= 1) mu += __shfl_xor(mu, off, 16);
    mu *= (1.0f / 16.0f);
    const float dd = vs - mu;
    float var = dd * dd;
    #pragma unroll
    for (int off = 1; off < 16; off <<= 1) var += __shfl_xor(var, off, 16);
    var *= (1.0f / 16.0f);
    out_v[idx] = dd / sqrtf(var + 1e-5f) * gamma[d] + beta[d];
}

// ---------------------------------------------------------------------------
// k3 v6: R5's verified 32x32x16 core + deep pipeline.
// qk[b,n,m] = sum_d (sum_a in[b,n,a] w[n,a,m,d]) * vsq[b,m,d]
// grid (8 mg, 128 nseg) = 1024 blocks; 512 thr = 8 waves = (nh 2) x (bg 4).
// Per phase (8 phases): 2 n staged; wave computes its n (nh), b-cols bg*32+lc,
// all 8 m (4 mp MFMAs). A=w^T rows=(mj,d)32, B=in^T cols=b32, K=a=16 exact.
// C layout (HW-verified R5): col=lane&31=b, row=(reg&3)+8*(reg>>2)+4*l5.
// Epilogue: 8 FMA/mj vs reg-resident vsq + 1 shfl_xor(32); 1 float4 store/lane.
// LDS pitch 24 ushorts: b128-aligned rows, floor-rate reads, <=4-way writes.
// Pipeline: 1 barrier/phase; stg consumes pr then ldg refills (2-phase-deep).
// ---------------------------------------------------------------------------
__global__ __launch_bounds__(512, 4) void k3_mfma3(const float* __restrict__ in,
                                                   const float* __restrict__ w,
                                                   const float* __restrict__ vsq,
                                                   float* __restrict__ qk) {
    const int m0 = blockIdx.x * 8;
    const int n0 = blockIdx.y * 16;
    const int t  = threadIdx.x;
    const int wv = t >> 6;
    const int nh = wv >> 2, bg = wv & 3;
    const int lane = t & 63;
    const int lc = lane & 31, l5 = lane >> 5;
    const int b  = bg * 32 + lc;

    // wt: [buf][nn][mp4][row32][WP]  row = mj*16 + d
    // it: [buf][nn][b128][WP]        a in cols 0..15
    __shared__ __align__(16) ushort wt[2][2][4 * 32 * WP];   // 2*2*3072 us
    __shared__ __align__(16) ushort it[2][2][128 * WP];      // 2*2*3072 us

    // vsq regs: vr[mm][h][e] = vsq[b][m0+mm][h*8 + 4*l5 + e]
    f32x4v vr[8][2];
    #pragma unroll
    for (int mm = 0; mm < 8; ++mm) {
        vr[mm][0] = *(const f32x4v*)(vsq + ((size_t)b * M + m0 + mm) * D + 4 * l5);
        vr[mm][1] = *(const f32x4v*)(vsq + ((size_t)b * M + m0 + mm) * D + 8 + 4 * l5);
    }

    // staging coords (decoupled from compute roles)
    const int s_nn = t >> 8, r = t & 255;
    const int wa1 = r & 7, wd4 = (r >> 3) & 3, wm_ = r >> 5;   // w: 2a x 1m x 4d
    const int ib_ = r >> 1, iq = r & 1;                        // in: 1b x 8a

    float4 pw[2], pi[2];
    auto ldg = [&](int ph) {
        const int n = n0 + ph * 2 + s_nn;
        #pragma unroll
        for (int j = 0; j < 2; ++j)
            pw[j] = *(const float4*)(
                w + ((size_t)(n * A + wa1 * 2 + j) * M + m0 + wm_) * D + wd4 * 4);
        #pragma unroll
        for (int j = 0; j < 2; ++j)
            pi[j] = *(const float4*)(in + (size_t)ib_ * NA + n * A + iq * 8 + j * 4);
    };
    auto stg = [&](int p) {
        ushort* wb_ = &wt[p][s_nn][((wm_ >> 1) * 32 + (wm_ & 1) * 16) * WP];
        #pragma unroll
        for (int k = 0; k < 4; ++k) {
            union { ushort s[2]; uint u; } v;
            v.s[0] = f2bf(pw[0][k]);
            v.s[1] = f2bf(pw[1][k]);
            *(uint*)(&wb_[(wd4 * 4 + k) * WP + wa1 * 2]) = v.u;
        }
        union { ushort s[8]; uint4 q; } pk;
        #pragma unroll
        for (int j = 0; j < 2; ++j) {
            pk.s[j * 4 + 0] = f2bf(pi[j].x); pk.s[j * 4 + 1] = f2bf(pi[j].y);
            pk.s[j * 4 + 2] = f2bf(pi[j].z); pk.s[j * 4 + 3] = f2bf(pi[j].w);
        }
        *(uint4*)(&it[p][s_nn][ib_ * WP + iq * 8]) = pk.q;
    };

    // prologue: stage buf0, prefetch phase-1 regs
    ldg(0);
    stg(0);
    ldg(1);
    __syncthreads();

    for (int ph = 0; ph < 8; ++ph) {
        const int p = ph & 1;
        // stage NEXT phase into other buffer (consumes pr), then refill pr.
        // Safe: between syncs all waves read buf p, write only buf p^1.
        if (ph < 7) stg(p ^ 1);
        if (ph < 6) ldg(ph + 2);

        const int n = n0 + ph * 2 + nh;
        const bfrag bf = ld_frag16(&it[p][nh][b * WP + l5 * 8]);
        float out4[4];
        #pragma unroll
        for (int mp = 0; mp < 4; ++mp) {
            const bfrag af = ld_frag16(&wt[p][nh][(mp * 32 + lc) * WP + l5 * 8]);
            f32x16 c = {};
            c = __builtin_amdgcn_mfma_f32_32x32x16_bf16(af, bf, c, 0, 0, 0);
            #pragma unroll
            for (int mj = 0; mj < 2; ++mj) {
                float s = 0.f;
                #pragma unroll
                for (int rr = 0; rr < 8; ++rr)
                    s += c[mj * 8 + rr] * vr[mp * 2 + mj][rr >> 2][rr & 3];
                s += __shfl_xor(s, 32);               // add other d-half
                if ((mp >> 1) == l5) out4[(mp & 1) * 2 + mj] = s;
            }
        }
        const float4 o = {out4[0], out4[1], out4[2], out4[3]};
        *(float4*)(qk + ((size_t)b * N + n) * M + m0 + l5 * 4) = o;
        __syncthreads();                              // one barrier per phase
    }
}

// ---------------------------------------------------------------------------
extern "C" void kernel_launch(void* const* d_in, const int* in_sizes, int n_in,
                              void* d_out, int out_size, void* d_ws, size_t ws_size,
                              hipStream_t stream) {
    const float* in    = (const float*)d_in[0];
    const float* w     = (const float*)d_in[1];
    const float* gamma = (const float*)d_in[2];
    const float* beta  = (const float*)d_in[3];
    float* out_qk = (float*)d_out;
    float* out_v  = out_qk + (size_t)B * N * M;

    int nch = 64;
    if (ws_size < (64 + 1) * C_ELEMS * sizeof(float)) nch = 16;
    if (ws_size < (16 + 1) * C_ELEMS * sizeof(float)) nch = 8;
    float* part = (float*)d_ws;
    float* vsq  = part + (size_t)nch * C_ELEMS;

    k1_mfma<<<dim3(4, nch), 512, 0, stream>>>(in, w, part, nch);
    k2_squash_ln<<<(int)(C_ELEMS / 256), 256, 0, stream>>>(part, gamma, beta, vsq, out_v, nch);
    k3_mfma3<<<dim3(8, 128), 512, 0, stream>>>(in, w, vsq, out_qk);
}